// Round 9
// baseline (101.886 us; speedup 1.0000x reference)
//
#include <hip/hip_runtime.h>
#include <cstdint>
#include <cstddef>

#define B_    32
#define P_    16384
#define C_    80
#define NOBJ_ 50

static constexpr size_t OFF_BP    = 1024;                        // int bp[B*NOBJ]
static constexpr size_t OFF_WP    = 16384;                       // float wp[B*P] (sign=pos)
static constexpr size_t SZ_BP32   = (size_t)B_ * P_ * 4;
static constexpr size_t OFF_PMAIN = OFF_WP + SZ_BP32;            // 2048*4 doubles
static constexpr size_t OFF_PSEL  = OFF_PMAIN + 2048 * 4 * 8;    // 32 doubles

__device__ __forceinline__ unsigned fkey(float f) {
    unsigned u = __float_as_uint(f);
    return (u & 0x80000000u) ? ~u : (u | 0x80000000u);
}

// Histogram add: 3 capped wave-aggregation peels (absorbs hot bins),
// then plain LDS atomicAdd fallback (diverse bins pipeline fine).
__device__ __forceinline__ void hist_add(unsigned bin, unsigned* hist) {
    int lane = threadIdx.x & 63;
    bool done = false;
    #pragma unroll
    for (int it = 0; it < 3; ++it) {
        unsigned long long active = __ballot(!done);
        if (!active) break;
        int leader = __ffsll((long long)active) - 1;
        unsigned lbin = __shfl(bin, leader);
        unsigned long long same = __ballot(!done && bin == lbin);
        if (!done && bin == lbin) {
            if (lane == leader) atomicAdd(&hist[bin], (unsigned)__popcll(same));
            done = true;
        }
    }
    if (!done) atomicAdd(&hist[bin], 1u);
}

__device__ double block_reduce_d(double v, double* sh, int nthreads) {
    int tid = threadIdx.x;
    sh[tid] = v; __syncthreads();
    for (int s = nthreads >> 1; s > 0; s >>= 1) {
        if (tid < s) sh[tid] += sh[tid + s];
        __syncthreads();
    }
    double r = sh[0]; __syncthreads();
    return r;
}

// Per-truth best prior (argmax over axis=1, first-index tie-break).
// Division-free: keep (inter, union), compare by cross-multiplication.
__global__ __launch_bounds__(256) void k_best_prior(
    const float* __restrict__ priors, const float* __restrict__ targets,
    int* __restrict__ bp)
{
    int t = blockIdx.x, b = blockIdx.y, tid = threadIdx.x;
    const float* tr = targets + (size_t)(b * NOBJ_ + t) * 6;
    float x1 = tr[0], y1 = tr[1], x2 = tr[2], y2 = tr[3];
    float areaA = (x2 - x1) * (y2 - y1);
    float bn = -1.f, bd = 1.f; int bi = 0;
    for (int p = tid; p < P_; p += 256) {
        float4 pr = ((const float4*)priors)[p];
        float bx1 = pr.x - pr.z*0.5f, by1 = pr.y - pr.w*0.5f;
        float bx2 = pr.x + pr.z*0.5f, by2 = pr.y + pr.w*0.5f;
        float areaB = (bx2 - bx1) * (by2 - by1);
        float lx = fmaxf(x1, bx1), ly = fmaxf(y1, by1);
        float rx = fminf(x2, bx2), ry = fminf(y2, by2);
        float iw = fmaxf(rx - lx, 0.f), ih = fmaxf(ry - ly, 0.f);
        float inter = iw * ih;
        float uni = areaA + areaB - inter;
        if (inter * bd > bn * uni) { bn = inter; bd = uni; bi = p; }
    }
    __shared__ float sn[256], sd[256];
    __shared__ int   si[256];
    sn[tid] = bn; sd[tid] = bd; si[tid] = bi; __syncthreads();
    for (int s = 128; s > 0; s >>= 1) {
        if (tid < s) {
            float lhs = sn[tid+s] * sd[tid], rhs = sn[tid] * sd[tid+s];
            if (lhs > rhs || (lhs == rhs && si[tid+s] < si[tid])) {
                sn[tid] = sn[tid+s]; sd[tid] = sd[tid+s]; si[tid] = si[tid+s];
            }
        }
        __syncthreads();
    }
    if (tid == 0) bp[b * NOBJ_ + t] = si[0];
}

// Fused main pass: per-prior match (division-free) + bp last-wins override +
// encode/smoothL1/CE. Full conf logsumexp ONLY for pos rows (lse cancels for
// tgt==0). Writes packed wp = pos ? -w : w. Partials to pmain (no atomics).
__global__ __launch_bounds__(256) void k_main(
    const float* __restrict__ loc, const float* __restrict__ conf,
    const float* __restrict__ obj, const float* __restrict__ priors,
    const float* __restrict__ targets, const int* __restrict__ bp,
    float* __restrict__ wp, double* __restrict__ pmain)
{
    int b = blockIdx.y;
    int row_base = blockIdx.x * 256;
    size_t base = (size_t)b * P_ + row_base;

    __shared__ float tg[NOBJ_ * 6];
    __shared__ float areaA[NOBJ_];
    __shared__ int   bpl[NOBJ_];
    __shared__ double wsum[4][4];
    for (int i = threadIdx.x; i < NOBJ_ * 6; i += 256) tg[i] = targets[(size_t)b * NOBJ_ * 6 + i];
    if (threadIdx.x < NOBJ_) bpl[threadIdx.x] = bp[b * NOBJ_ + threadIdx.x];
    __syncthreads();
    if (threadIdx.x < NOBJ_) {
        int t = threadIdx.x;
        areaA[t] = (tg[t*6+2] - tg[t*6+0]) * (tg[t*6+3] - tg[t*6+1]);
    }
    __syncthreads();

    int p = row_base + threadIdx.x;
    size_t ip = base + threadIdx.x;

    // ---- match: best truth for this prior (first-index tie-break) ----
    float4 prv = ((const float4*)priors)[p];
    float bx1 = prv.x - prv.z*0.5f, by1 = prv.y - prv.w*0.5f;
    float bx2 = prv.x + prv.z*0.5f, by2 = prv.y + prv.w*0.5f;
    float areaB = (bx2 - bx1) * (by2 - by1);
    float bn = -1.f, bd = 1.f; int ti = 0;
    for (int t = 0; t < NOBJ_; ++t) {
        float lx = fmaxf(tg[t*6+0], bx1), ly = fmaxf(tg[t*6+1], by1);
        float rx = fminf(tg[t*6+2], bx2), ry = fminf(tg[t*6+3], by2);
        float iw = fmaxf(rx - lx, 0.f), ih = fmaxf(ry - ly, 0.f);
        float inter = iw * ih;
        float uni = areaA[t] + areaB - inter;
        if (inter * bd > bn * uni) { bn = inter; bd = uni; ti = t; }
    }
    bool pos = (2.0f * bn >= bd);     // iou >= 0.5
    // ---- scatter override (last-wins, numpy in-order semantics) ----
    for (int j = 0; j < NOBJ_; ++j) {
        if (bpl[j] == p) { pos = true; ti = j; }
    }

    float w  = tg[ti*6+5];
    int  tgt = pos ? (int)tg[ti*6+4] : 0;

    // encode + smooth L1
    float tx1 = tg[ti*6+0], ty1 = tg[ti*6+1], tx2 = tg[ti*6+2], ty2 = tg[ti*6+3];
    float gx = ((tx1 + tx2) * 0.5f - prv.x) / (0.1f * prv.z);
    float gy = ((ty1 + ty2) * 0.5f - prv.y) / (0.1f * prv.w);
    float gw = __logf((tx2 - tx1) / prv.z) * 5.0f;
    float gh = __logf((ty2 - ty1) / prv.w) * 5.0f;

    float4 l4 = ((const float4*)loc)[ip];
    float sl1 = 0.f;
    {
        float lrk[4] = {l4.x, l4.y, l4.z, l4.w};
        float g[4] = {gx, gy, gw, gh};
        #pragma unroll
        for (int k = 0; k < 4; ++k) {
            float d = lrk[k] - g[k];
            float ad = fabsf(d);
            sl1 += (ad < 1.0f) ? 0.5f * d * d : ad - 0.5f;
        }
    }

    float2 ob = ((const float2*)obj)[ip];
    float o0 = ob.x, o1 = ob.y;
    float mo = fmaxf(o0, o1);
    float lae = mo + __logf(__expf(o0 - mo) + __expf(o1 - mo));

    float ce_o = lae - (pos ? o1 : o0);
    float ce_c;
    if (tgt == 0) {
        ce_c = lae - o0;                 // lse_conf cancels for background tgt
    } else {
        // pos rows only (~1-5%): full-row logsumexp, two-pass
        const float4* cr = (const float4*)(conf + ip * C_);
        float m = -INFINITY;
        #pragma unroll 4
        for (int k = 0; k < C_/4; ++k) {
            float4 v = cr[k];
            m = fmaxf(m, fmaxf(fmaxf(v.x, v.y), fmaxf(v.z, v.w)));
        }
        float s = 0.f;
        #pragma unroll 4
        for (int k = 0; k < C_/4; ++k) {
            float4 v = cr[k];
            s += __expf(v.x - m) + __expf(v.y - m) + __expf(v.z - m) + __expf(v.w - m);
        }
        float lse = m + __logf(s);
        float ctgt = conf[ip * C_ + (tgt - 1)];
        ce_c = lse + lae - o1 - ctgt;
    }

    wp[ip] = pos ? -w : w;

    double v0 = pos ? (double)(sl1 * w)  : 0.0;
    double v1 = pos ? (double)(ce_c * w) : 0.0;
    double v2 = pos ? (double)(ce_o * w) : 0.0;
    double v3 = pos ? (double)w          : 0.0;

    #pragma unroll
    for (int d = 32; d; d >>= 1) {
        v0 += __shfl_xor(v0, d);
        v1 += __shfl_xor(v1, d);
        v2 += __shfl_xor(v2, d);
        v3 += __shfl_xor(v3, d);
    }
    int wid = threadIdx.x >> 6, lane = threadIdx.x & 63;
    if (lane == 0) { wsum[wid][0] = v0; wsum[wid][1] = v1; wsum[wid][2] = v2; wsum[wid][3] = v3; }
    __syncthreads();
    if (threadIdx.x == 0) {
        double t0 = 0, t1 = 0, t2 = 0, t3 = 0;
        #pragma unroll
        for (int i = 0; i < 4; ++i) { t0 += wsum[i][0]; t1 += wsum[i][1]; t2 += wsum[i][2]; t3 += wsum[i][3]; }
        size_t flat = (size_t)b * gridDim.x + blockIdx.x;
        pmain[flat*4+0] = t0; pmain[flat*4+1] = t1; pmain[flat*4+2] = t2; pmain[flat*4+3] = t3;
    }
}

#define SEL_T 1024
#define TIE_CAP 1024

// Hierarchical suffix scan: per-wave shfl_down scan + 16 wave totals.
__device__ __forceinline__ void suffix_scan_2048(unsigned* c, unsigned* wtot) {
    int tid = threadIdx.x;
    int lane = tid & 63, wid = tid >> 6;
    unsigned lo = c[2*tid], hi = c[2*tid+1];
    unsigned s_hi = hi;
    unsigned s_lo = lo + hi;
    unsigned tot = s_lo;
    unsigned run = tot;
    #pragma unroll
    for (int d = 1; d < 64; d <<= 1) {
        unsigned o = __shfl_down(run, d);
        if (lane + d < 64) run += o;
    }
    if (lane == 0) wtot[wid] = run;
    __syncthreads();
    unsigned woff = 0;
    #pragma unroll
    for (int w = 0; w < 16; ++w) if (w > wid) woff += wtot[w];
    unsigned base = woff + (run - tot);
    __syncthreads();
    c[2*tid]   = base + s_lo;
    c[2*tid+1] = base + s_hi;
    __syncthreads();
}

__device__ __forceinline__ void find_bin(unsigned* c, int K, int* s_bin, int* s_pre) {
    int tid = threadIdx.x;
    #pragma unroll
    for (int i = 0; i < 2; ++i) {
        int bb = tid + i * 1024;
        unsigned cb = c[bb];
        unsigned cn = (bb == 2047) ? 0u : c[bb + 1];
        if (cb >= (unsigned)K && cn < (unsigned)K) { *s_bin = bb; *s_pre = (int)cn; }
    }
    __syncthreads();
}

// Exact top-K selection per batch (conf & obj branches are IDENTICAL:
// key(neg) = logaddexp(o0,o1)-o0 for both). Key recomputed from obj on the
// fly; pos rows (wp<0) have key 0. One launch serves both losses.
__global__ __launch_bounds__(SEL_T) void k_select(
    const float* __restrict__ obj, const float* __restrict__ wp,
    const double* __restrict__ pmain, double* __restrict__ psel)
{
    int b = blockIdx.x;
    int tid = threadIdx.x;

    __shared__ int sK;
    if (tid < 32) {
        double pn = pmain[(size_t)(b * 64 + tid) * 4 + 3]
                  + pmain[(size_t)(b * 64 + 32 + tid) * 4 + 3];
        #pragma unroll
        for (int d = 16; d; d >>= 1) pn += __shfl_xor(pn, d);
        if (tid == 0) {
            int np = (int)pn;
            int nn = 3 * np;
            sK = nn < (P_ - 1) ? nn : (P_ - 1);
        }
    }
    __syncthreads();
    int K = sK;
    if (K <= 0) { if (tid == 0) psel[b] = 0.0; return; }

    const float2* o2 = (const float2*)(obj + (size_t)b * P_ * 2);
    const float*  wr = wp + (size_t)b * P_;

    __shared__ unsigned hist[2048];
    __shared__ unsigned wtot[16];
    __shared__ int s_bin, s_pre;
    __shared__ int tcnt;
    __shared__ int tlist[TIE_CAP];
    __shared__ double rd[SEL_T];

    // key for row i: pos ? 0 : lae - o0  (recomputed identically each pass)
    #define KEY_AT(i, kvar, vvar)                                          \
        {                                                                  \
            float2 _o = o2[i];                                             \
            float _m = fmaxf(_o.x, _o.y);                                  \
            float _lae = _m + __logf(__expf(_o.x - _m) + __expf(_o.y - _m));\
            vvar = _lae - _o.x;                                            \
            if (wr[i] < 0.f) vvar = 0.f;                                   \
            kvar = fkey(vvar);                                             \
        }

    // ---- pass 1: bits [31:21] ----
    hist[tid] = 0; hist[tid + 1024] = 0;
    __syncthreads();
    for (int i = tid; i < P_; i += SEL_T) {
        unsigned k; float v;
        KEY_AT(i, k, v);
        hist_add(k >> 21, hist);
    }
    __syncthreads();
    suffix_scan_2048(hist, wtot);
    find_bin(hist, K, &s_bin, &s_pre);
    int bin1 = s_bin, pre1 = s_pre;
    __syncthreads();

    // ---- pass 2: bits [20:10] ----
    hist[tid] = 0; hist[tid + 1024] = 0;
    __syncthreads();
    for (int i = tid; i < P_; i += SEL_T) {
        unsigned k; float v;
        KEY_AT(i, k, v);
        if ((int)(k >> 21) == bin1) hist_add((k >> 10) & 0x7FFu, hist);
    }
    __syncthreads();
    suffix_scan_2048(hist, wtot);
    find_bin(hist, K - pre1, &s_bin, &s_pre);
    int bin2 = s_bin, pre2 = s_pre;
    __syncthreads();

    // ---- pass 3: bits [9:0] ----
    hist[tid] = 0; hist[tid + 1024] = 0;
    __syncthreads();
    unsigned hi21 = ((unsigned)bin1 << 11) | (unsigned)bin2;
    for (int i = tid; i < P_; i += SEL_T) {
        unsigned k; float v;
        KEY_AT(i, k, v);
        if ((k >> 10) == hi21) hist_add(k & 0x3FFu, hist);
    }
    __syncthreads();
    suffix_scan_2048(hist, wtot);
    find_bin(hist, K - pre1 - pre2, &s_bin, &s_pre);
    int bin3 = s_bin, pre3 = s_pre;
    __syncthreads();

    unsigned T = (hi21 << 10) | (unsigned)bin3;
    int mslots = K - (pre1 + pre2 + pre3);

    // ---- sum k > T; gather key==T ties ----
    if (tid == 0) tcnt = 0;
    __syncthreads();
    double sum = 0.0;
    for (int i = tid; i < P_; i += SEL_T) {
        unsigned k; float v;
        KEY_AT(i, k, v);
        float w = wr[i];
        bool neg = (w >= 0.f);
        if (k > T) {
            if (neg) sum += (double)v * (double)w;
        } else if (k == T && neg && v != 0.0f) {
            int slot = atomicAdd(&tcnt, 1);
            if (slot < TIE_CAP) tlist[slot] = i;
        }
    }
    __syncthreads();
    int n = tcnt < TIE_CAP ? tcnt : TIE_CAP;
    if (tid < n) {
        int myp = tlist[tid];
        bool sel;
        if (n <= mslots) {
            sel = true;
        } else {
            int r = 0;
            for (int j = 0; j < n; ++j) if (tlist[j] < myp) ++r;
            sel = (r < mslots);
        }
        if (sel) {
            unsigned k; float v;
            KEY_AT(myp, k, v);
            sum += (double)v * (double)wr[myp];
        }
    }
    #undef KEY_AT
    double r = block_reduce_d(sum, rd, SEL_T);
    if (tid == 0) psel[b] = r;
}

// Final: reduce pmain (2048x4 doubles) + psel (32, shared by both branches).
__global__ __launch_bounds__(1024) void k_final(
    const double* __restrict__ pmain, const double* __restrict__ psel,
    float* __restrict__ out)
{
    int tid = threadIdx.x;
    int lane = tid & 63, wid = tid >> 6;
    double s0 = 0, s1 = 0, s2 = 0, s3 = 0;
    for (int i = tid; i < 2048; i += 1024) {
        const double* pr = pmain + (size_t)i * 4;
        s0 += pr[0]; s1 += pr[1]; s2 += pr[2]; s3 += pr[3];
    }
    #pragma unroll
    for (int d = 32; d; d >>= 1) {
        s0 += __shfl_xor(s0, d); s1 += __shfl_xor(s1, d);
        s2 += __shfl_xor(s2, d); s3 += __shfl_xor(s3, d);
    }
    __shared__ double sh[16][4];
    if (lane == 0) { sh[wid][0] = s0; sh[wid][1] = s1; sh[wid][2] = s2; sh[wid][3] = s3; }
    __syncthreads();
    if (tid == 0) {
        double a0 = 0, a1 = 0, a2 = 0, N = 0;
        #pragma unroll
        for (int i = 0; i < 16; ++i) { a0 += sh[i][0]; a1 += sh[i][1]; a2 += sh[i][2]; N += sh[i][3]; }
        double sel = 0;
        for (int i = 0; i < B_; ++i) sel += psel[i];
        out[0] = (float)(a0 / N);
        out[1] = (float)((a1 + sel) / N);
        out[2] = (float)((a2 + sel) / N);
    }
}

extern "C" void kernel_launch(void* const* d_in, const int* in_sizes, int n_in,
                              void* d_out, int out_size, void* d_ws, size_t ws_size,
                              hipStream_t stream)
{
    const float* loc     = (const float*)d_in[0];
    const float* conf    = (const float*)d_in[1];
    const float* obj     = (const float*)d_in[2];
    const float* priors  = (const float*)d_in[3];
    const float* targets = (const float*)d_in[4];
    float* out = (float*)d_out;

    char* ws = (char*)d_ws;
    int*    bp    = (int*)(ws + OFF_BP);
    float*  wpArr = (float*)(ws + OFF_WP);
    double* pmain = (double*)(ws + OFF_PMAIN);
    double* psel  = (double*)(ws + OFF_PSEL);

    k_best_prior <<<dim3(NOBJ_, B_), 256, 0, stream>>>(priors, targets, bp);
    k_main       <<<dim3(P_/256, B_), 256, 0, stream>>>(loc, conf, obj, priors, targets,
                                                        bp, wpArr, pmain);
    k_select     <<<B_, SEL_T, 0, stream>>>(obj, wpArr, pmain, psel);
    k_final      <<<1, 1024, 0, stream>>>(pmain, psel, out);
}

// Round 10
// 95.328 us; speedup vs baseline: 1.0688x; 1.0688x over previous
//
#include <hip/hip_runtime.h>
#include <cstdint>
#include <cstddef>

#define B_    32
#define P_    16384
#define C_    80
#define NOBJ_ 50

static constexpr size_t OFF_BP    = 1024;                        // int bp[B*NOBJ]
static constexpr size_t OFF_WP    = 16384;                       // float wp[B*P] (sign=pos)
static constexpr size_t SZ_BP32   = (size_t)B_ * P_ * 4;
static constexpr size_t OFF_MINE  = OFF_WP + SZ_BP32;            // float mine[B*P] (-1 = pos)
static constexpr size_t OFF_PMAIN = OFF_MINE + SZ_BP32;          // 2048*4 doubles
static constexpr size_t OFF_PSEL  = OFF_PMAIN + 2048 * 4 * 8;    // 32 doubles

__device__ __forceinline__ unsigned fkey(float f) {
    unsigned u = __float_as_uint(f);
    return (u & 0x80000000u) ? ~u : (u | 0x80000000u);
}

// Histogram add: 3 capped wave-aggregation peels (absorbs hot bins),
// then plain LDS atomicAdd fallback (diverse bins pipeline fine).
__device__ __forceinline__ void hist_add(unsigned bin, unsigned* hist) {
    int lane = threadIdx.x & 63;
    bool done = false;
    #pragma unroll
    for (int it = 0; it < 3; ++it) {
        unsigned long long active = __ballot(!done);
        if (!active) break;
        int leader = __ffsll((long long)active) - 1;
        unsigned lbin = __shfl(bin, leader);
        unsigned long long same = __ballot(!done && bin == lbin);
        if (!done && bin == lbin) {
            if (lane == leader) atomicAdd(&hist[bin], (unsigned)__popcll(same));
            done = true;
        }
    }
    if (!done) atomicAdd(&hist[bin], 1u);
}

__device__ double block_reduce_d(double v, double* sh, int nthreads) {
    int tid = threadIdx.x;
    sh[tid] = v; __syncthreads();
    for (int s = nthreads >> 1; s > 0; s >>= 1) {
        if (tid < s) sh[tid] += sh[tid + s];
        __syncthreads();
    }
    double r = sh[0]; __syncthreads();
    return r;
}

// Per-truth best prior (argmax over axis=1, first-index tie-break).
// Division-free: keep (inter, union), compare by cross-multiplication.
__global__ __launch_bounds__(256) void k_best_prior(
    const float* __restrict__ priors, const float* __restrict__ targets,
    int* __restrict__ bp)
{
    int t = blockIdx.x, b = blockIdx.y, tid = threadIdx.x;
    const float* tr = targets + (size_t)(b * NOBJ_ + t) * 6;
    float x1 = tr[0], y1 = tr[1], x2 = tr[2], y2 = tr[3];
    float areaA = (x2 - x1) * (y2 - y1);
    float bn = -1.f, bd = 1.f; int bi = 0;
    for (int p = tid; p < P_; p += 256) {
        float4 pr = ((const float4*)priors)[p];
        float bx1 = pr.x - pr.z*0.5f, by1 = pr.y - pr.w*0.5f;
        float bx2 = pr.x + pr.z*0.5f, by2 = pr.y + pr.w*0.5f;
        float areaB = (bx2 - bx1) * (by2 - by1);
        float lx = fmaxf(x1, bx1), ly = fmaxf(y1, by1);
        float rx = fminf(x2, bx2), ry = fminf(y2, by2);
        float iw = fmaxf(rx - lx, 0.f), ih = fmaxf(ry - ly, 0.f);
        float inter = iw * ih;
        float uni = areaA + areaB - inter;
        if (inter * bd > bn * uni) { bn = inter; bd = uni; bi = p; }
    }
    __shared__ float sn[256], sd[256];
    __shared__ int   si[256];
    sn[tid] = bn; sd[tid] = bd; si[tid] = bi; __syncthreads();
    for (int s = 128; s > 0; s >>= 1) {
        if (tid < s) {
            float lhs = sn[tid+s] * sd[tid], rhs = sn[tid] * sd[tid+s];
            if (lhs > rhs || (lhs == rhs && si[tid+s] < si[tid])) {
                sn[tid] = sn[tid+s]; sd[tid] = sd[tid+s]; si[tid] = si[tid+s];
            }
        }
        __syncthreads();
    }
    if (tid == 0) bp[b * NOBJ_ + t] = si[0];
}

// Fused main pass: per-prior match (division-free) + bp last-wins override +
// encode/smoothL1/CE. Full conf logsumexp ONLY for pos rows (lse cancels for
// tgt==0). Writes wp = pos ? -w : w and mine = pos ? -1 : ce_o (the shared
// mining key for BOTH branches). Partials to pmain (no atomics).
__global__ __launch_bounds__(256) void k_main(
    const float* __restrict__ loc, const float* __restrict__ conf,
    const float* __restrict__ obj, const float* __restrict__ priors,
    const float* __restrict__ targets, const int* __restrict__ bp,
    float* __restrict__ wp, float* __restrict__ mine,
    double* __restrict__ pmain)
{
    int b = blockIdx.y;
    int row_base = blockIdx.x * 256;
    size_t base = (size_t)b * P_ + row_base;

    __shared__ float tg[NOBJ_ * 6];
    __shared__ float areaA[NOBJ_];
    __shared__ int   bpl[NOBJ_];
    __shared__ double wsum[4][4];
    for (int i = threadIdx.x; i < NOBJ_ * 6; i += 256) tg[i] = targets[(size_t)b * NOBJ_ * 6 + i];
    if (threadIdx.x < NOBJ_) bpl[threadIdx.x] = bp[b * NOBJ_ + threadIdx.x];
    __syncthreads();
    if (threadIdx.x < NOBJ_) {
        int t = threadIdx.x;
        areaA[t] = (tg[t*6+2] - tg[t*6+0]) * (tg[t*6+3] - tg[t*6+1]);
    }
    __syncthreads();

    int p = row_base + threadIdx.x;
    size_t ip = base + threadIdx.x;

    // ---- match: best truth for this prior (first-index tie-break) ----
    float4 prv = ((const float4*)priors)[p];
    float bx1 = prv.x - prv.z*0.5f, by1 = prv.y - prv.w*0.5f;
    float bx2 = prv.x + prv.z*0.5f, by2 = prv.y + prv.w*0.5f;
    float areaB = (bx2 - bx1) * (by2 - by1);
    float bn = -1.f, bd = 1.f; int ti = 0;
    for (int t = 0; t < NOBJ_; ++t) {
        float lx = fmaxf(tg[t*6+0], bx1), ly = fmaxf(tg[t*6+1], by1);
        float rx = fminf(tg[t*6+2], bx2), ry = fminf(tg[t*6+3], by2);
        float iw = fmaxf(rx - lx, 0.f), ih = fmaxf(ry - ly, 0.f);
        float inter = iw * ih;
        float uni = areaA[t] + areaB - inter;
        if (inter * bd > bn * uni) { bn = inter; bd = uni; ti = t; }
    }
    bool pos = (2.0f * bn >= bd);     // iou >= 0.5
    // ---- scatter override (last-wins, numpy in-order semantics) ----
    for (int j = 0; j < NOBJ_; ++j) {
        if (bpl[j] == p) { pos = true; ti = j; }
    }

    float w  = tg[ti*6+5];
    int  tgt = pos ? (int)tg[ti*6+4] : 0;

    // encode + smooth L1
    float tx1 = tg[ti*6+0], ty1 = tg[ti*6+1], tx2 = tg[ti*6+2], ty2 = tg[ti*6+3];
    float gx = ((tx1 + tx2) * 0.5f - prv.x) / (0.1f * prv.z);
    float gy = ((ty1 + ty2) * 0.5f - prv.y) / (0.1f * prv.w);
    float gw = __logf((tx2 - tx1) / prv.z) * 5.0f;
    float gh = __logf((ty2 - ty1) / prv.w) * 5.0f;

    float4 l4 = ((const float4*)loc)[ip];
    float sl1 = 0.f;
    {
        float lrk[4] = {l4.x, l4.y, l4.z, l4.w};
        float g[4] = {gx, gy, gw, gh};
        #pragma unroll
        for (int k = 0; k < 4; ++k) {
            float d = lrk[k] - g[k];
            float ad = fabsf(d);
            sl1 += (ad < 1.0f) ? 0.5f * d * d : ad - 0.5f;
        }
    }

    float2 ob = ((const float2*)obj)[ip];
    float o0 = ob.x, o1 = ob.y;
    float mo = fmaxf(o0, o1);
    float lae = mo + __logf(__expf(o0 - mo) + __expf(o1 - mo));

    float ce_o = lae - (pos ? o1 : o0);
    float ce_c;
    if (tgt == 0) {
        ce_c = lae - o0;                 // lse_conf cancels for background tgt
    } else {
        // pos rows only (~1-5%): full-row logsumexp, two-pass
        const float4* cr = (const float4*)(conf + ip * C_);
        float m = -INFINITY;
        #pragma unroll 4
        for (int k = 0; k < C_/4; ++k) {
            float4 v = cr[k];
            m = fmaxf(m, fmaxf(fmaxf(v.x, v.y), fmaxf(v.z, v.w)));
        }
        float s = 0.f;
        #pragma unroll 4
        for (int k = 0; k < C_/4; ++k) {
            float4 v = cr[k];
            s += __expf(v.x - m) + __expf(v.y - m) + __expf(v.z - m) + __expf(v.w - m);
        }
        float lse = m + __logf(s);
        float ctgt = conf[ip * C_ + (tgt - 1)];
        ce_c = lse + lae - o1 - ctgt;
    }

    wp[ip]   = pos ? -w : w;
    mine[ip] = pos ? -1.0f : ce_o;   // ce_o >= 0 always; -1 marks pos

    double v0 = pos ? (double)(sl1 * w)  : 0.0;
    double v1 = pos ? (double)(ce_c * w) : 0.0;
    double v2 = pos ? (double)(ce_o * w) : 0.0;
    double v3 = pos ? (double)w          : 0.0;

    #pragma unroll
    for (int d = 32; d; d >>= 1) {
        v0 += __shfl_xor(v0, d);
        v1 += __shfl_xor(v1, d);
        v2 += __shfl_xor(v2, d);
        v3 += __shfl_xor(v3, d);
    }
    int wid = threadIdx.x >> 6, lane = threadIdx.x & 63;
    if (lane == 0) { wsum[wid][0] = v0; wsum[wid][1] = v1; wsum[wid][2] = v2; wsum[wid][3] = v3; }
    __syncthreads();
    if (threadIdx.x == 0) {
        double t0 = 0, t1 = 0, t2 = 0, t3 = 0;
        #pragma unroll
        for (int i = 0; i < 4; ++i) { t0 += wsum[i][0]; t1 += wsum[i][1]; t2 += wsum[i][2]; t3 += wsum[i][3]; }
        size_t flat = (size_t)b * gridDim.x + blockIdx.x;
        pmain[flat*4+0] = t0; pmain[flat*4+1] = t1; pmain[flat*4+2] = t2; pmain[flat*4+3] = t3;
    }
}

#define SEL_T 1024
#define TIE_CAP 1024

// Hierarchical suffix scan: per-wave shfl_down scan + 16 wave totals.
__device__ __forceinline__ void suffix_scan_2048(unsigned* c, unsigned* wtot) {
    int tid = threadIdx.x;
    int lane = tid & 63, wid = tid >> 6;
    unsigned lo = c[2*tid], hi = c[2*tid+1];
    unsigned s_hi = hi;
    unsigned s_lo = lo + hi;
    unsigned tot = s_lo;
    unsigned run = tot;
    #pragma unroll
    for (int d = 1; d < 64; d <<= 1) {
        unsigned o = __shfl_down(run, d);
        if (lane + d < 64) run += o;
    }
    if (lane == 0) wtot[wid] = run;
    __syncthreads();
    unsigned woff = 0;
    #pragma unroll
    for (int w = 0; w < 16; ++w) if (w > wid) woff += wtot[w];
    unsigned base = woff + (run - tot);
    __syncthreads();
    c[2*tid]   = base + s_lo;
    c[2*tid+1] = base + s_hi;
    __syncthreads();
}

__device__ __forceinline__ void find_bin(unsigned* c, int K, int* s_bin, int* s_pre) {
    int tid = threadIdx.x;
    #pragma unroll
    for (int i = 0; i < 2; ++i) {
        int bb = tid + i * 1024;
        unsigned cb = c[bb];
        unsigned cn = (bb == 2047) ? 0u : c[bb + 1];
        if (cb >= (unsigned)K && cn < (unsigned)K) { *s_bin = bb; *s_pre = (int)cn; }
    }
    __syncthreads();
}

// Exact top-K selection per batch (conf & obj branches share the identical
// key; k_main precomputed mine = pos ? -1 : ce_o). One launch, both losses.
__global__ __launch_bounds__(SEL_T) void k_select(
    const float* __restrict__ mine, const float* __restrict__ wp,
    const double* __restrict__ pmain, double* __restrict__ psel)
{
    int b = blockIdx.x;
    int tid = threadIdx.x;

    __shared__ int sK;
    if (tid < 32) {
        double pn = pmain[(size_t)(b * 64 + tid) * 4 + 3]
                  + pmain[(size_t)(b * 64 + 32 + tid) * 4 + 3];
        #pragma unroll
        for (int d = 16; d; d >>= 1) pn += __shfl_xor(pn, d);
        if (tid == 0) {
            int np = (int)pn;
            int nn = 3 * np;
            sK = nn < (P_ - 1) ? nn : (P_ - 1);
        }
    }
    __syncthreads();
    int K = sK;
    if (K <= 0) { if (tid == 0) psel[b] = 0.0; return; }

    const float* mrow = mine + (size_t)b * P_;
    const float* wr   = wp   + (size_t)b * P_;
    const float4* m4  = (const float4*)mrow;

    __shared__ unsigned hist[2048];
    __shared__ unsigned wtot[16];
    __shared__ int s_bin, s_pre;
    __shared__ int tcnt;
    __shared__ int tlist[TIE_CAP];
    __shared__ double rd[SEL_T];

    // ranking value: pos rows (mine<0) rank as 0.0 (matches reference)
    #define KEYV(raw) ((raw) < 0.f ? 0.f : (raw))

    // ---- pass 1: bits [31:21] ----
    hist[tid] = 0; hist[tid + 1024] = 0;
    __syncthreads();
    for (int i = tid; i < P_/4; i += SEL_T) {
        float4 v = m4[i];
        hist_add(fkey(KEYV(v.x)) >> 21, hist);
        hist_add(fkey(KEYV(v.y)) >> 21, hist);
        hist_add(fkey(KEYV(v.z)) >> 21, hist);
        hist_add(fkey(KEYV(v.w)) >> 21, hist);
    }
    __syncthreads();
    suffix_scan_2048(hist, wtot);
    find_bin(hist, K, &s_bin, &s_pre);
    int bin1 = s_bin, pre1 = s_pre;
    __syncthreads();

    // ---- pass 2: bits [20:10] ----
    hist[tid] = 0; hist[tid + 1024] = 0;
    __syncthreads();
    for (int i = tid; i < P_/4; i += SEL_T) {
        float4 v = m4[i];
        unsigned k0 = fkey(KEYV(v.x)), k1 = fkey(KEYV(v.y));
        unsigned k2 = fkey(KEYV(v.z)), k3 = fkey(KEYV(v.w));
        if ((int)(k0 >> 21) == bin1) hist_add((k0 >> 10) & 0x7FFu, hist);
        if ((int)(k1 >> 21) == bin1) hist_add((k1 >> 10) & 0x7FFu, hist);
        if ((int)(k2 >> 21) == bin1) hist_add((k2 >> 10) & 0x7FFu, hist);
        if ((int)(k3 >> 21) == bin1) hist_add((k3 >> 10) & 0x7FFu, hist);
    }
    __syncthreads();
    suffix_scan_2048(hist, wtot);
    find_bin(hist, K - pre1, &s_bin, &s_pre);
    int bin2 = s_bin, pre2 = s_pre;
    __syncthreads();

    // ---- pass 3: bits [9:0] ----
    hist[tid] = 0; hist[tid + 1024] = 0;
    __syncthreads();
    unsigned hi21 = ((unsigned)bin1 << 11) | (unsigned)bin2;
    for (int i = tid; i < P_/4; i += SEL_T) {
        float4 v = m4[i];
        unsigned k0 = fkey(KEYV(v.x)), k1 = fkey(KEYV(v.y));
        unsigned k2 = fkey(KEYV(v.z)), k3 = fkey(KEYV(v.w));
        if ((k0 >> 10) == hi21) hist_add(k0 & 0x3FFu, hist);
        if ((k1 >> 10) == hi21) hist_add(k1 & 0x3FFu, hist);
        if ((k2 >> 10) == hi21) hist_add(k2 & 0x3FFu, hist);
        if ((k3 >> 10) == hi21) hist_add(k3 & 0x3FFu, hist);
    }
    __syncthreads();
    suffix_scan_2048(hist, wtot);
    find_bin(hist, K - pre1 - pre2, &s_bin, &s_pre);
    int bin3 = s_bin, pre3 = s_pre;
    __syncthreads();

    unsigned T = (hi21 << 10) | (unsigned)bin3;
    int mslots = K - (pre1 + pre2 + pre3);

    // ---- sum k > T; gather key==T ties (neg, nonzero only) ----
    if (tid == 0) tcnt = 0;
    __syncthreads();
    double sum = 0.0;
    for (int i = tid; i < P_; i += SEL_T) {
        float raw = mrow[i];
        bool neg = raw >= 0.f;
        float v = neg ? raw : 0.f;
        unsigned k = fkey(v);
        if (k > T) {
            if (neg) sum += (double)v * (double)wr[i];
        } else if (k == T && neg && v != 0.0f) {
            int slot = atomicAdd(&tcnt, 1);
            if (slot < TIE_CAP) tlist[slot] = i;
        }
    }
    __syncthreads();
    int n = tcnt < TIE_CAP ? tcnt : TIE_CAP;
    if (tid < n) {
        int myp = tlist[tid];
        bool sel;
        if (n <= mslots) {
            sel = true;
        } else {
            int r = 0;
            for (int j = 0; j < n; ++j) if (tlist[j] < myp) ++r;
            sel = (r < mslots);
        }
        if (sel) sum += (double)mrow[myp] * (double)wr[myp];
    }
    #undef KEYV
    double r = block_reduce_d(sum, rd, SEL_T);
    if (tid == 0) psel[b] = r;
}

// Final: reduce pmain (2048x4 doubles) + psel (32, shared by both branches).
__global__ __launch_bounds__(1024) void k_final(
    const double* __restrict__ pmain, const double* __restrict__ psel,
    float* __restrict__ out)
{
    int tid = threadIdx.x;
    int lane = tid & 63, wid = tid >> 6;
    double s0 = 0, s1 = 0, s2 = 0, s3 = 0;
    for (int i = tid; i < 2048; i += 1024) {
        const double* pr = pmain + (size_t)i * 4;
        s0 += pr[0]; s1 += pr[1]; s2 += pr[2]; s3 += pr[3];
    }
    #pragma unroll
    for (int d = 32; d; d >>= 1) {
        s0 += __shfl_xor(s0, d); s1 += __shfl_xor(s1, d);
        s2 += __shfl_xor(s2, d); s3 += __shfl_xor(s3, d);
    }
    __shared__ double sh[16][4];
    if (lane == 0) { sh[wid][0] = s0; sh[wid][1] = s1; sh[wid][2] = s2; sh[wid][3] = s3; }
    __syncthreads();
    if (tid == 0) {
        double a0 = 0, a1 = 0, a2 = 0, N = 0;
        #pragma unroll
        for (int i = 0; i < 16; ++i) { a0 += sh[i][0]; a1 += sh[i][1]; a2 += sh[i][2]; N += sh[i][3]; }
        double sel = 0;
        for (int i = 0; i < B_; ++i) sel += psel[i];
        out[0] = (float)(a0 / N);
        out[1] = (float)((a1 + sel) / N);
        out[2] = (float)((a2 + sel) / N);
    }
}

extern "C" void kernel_launch(void* const* d_in, const int* in_sizes, int n_in,
                              void* d_out, int out_size, void* d_ws, size_t ws_size,
                              hipStream_t stream)
{
    const float* loc     = (const float*)d_in[0];
    const float* conf    = (const float*)d_in[1];
    const float* obj     = (const float*)d_in[2];
    const float* priors  = (const float*)d_in[3];
    const float* targets = (const float*)d_in[4];
    float* out = (float*)d_out;

    char* ws = (char*)d_ws;
    int*    bp    = (int*)(ws + OFF_BP);
    float*  wpArr = (float*)(ws + OFF_WP);
    float*  mine  = (float*)(ws + OFF_MINE);
    double* pmain = (double*)(ws + OFF_PMAIN);
    double* psel  = (double*)(ws + OFF_PSEL);

    k_best_prior <<<dim3(NOBJ_, B_), 256, 0, stream>>>(priors, targets, bp);
    k_main       <<<dim3(P_/256, B_), 256, 0, stream>>>(loc, conf, obj, priors, targets,
                                                        bp, wpArr, mine, pmain);
    k_select     <<<B_, SEL_T, 0, stream>>>(mine, wpArr, pmain, psel);
    k_final      <<<1, 1024, 0, stream>>>(pmain, psel, out);
}